// Round 1
// baseline (2322.080 us; speedup 1.0000x reference)
//
#include <hip/hip_runtime.h>
#include <stdint.h>

#define B_ 8
#define N_ 2048
#define D_ 1024
#define E_ 8
#define F_ 4096
#define H_ 1024
#define T_ (B_*N_)

typedef unsigned short u16;
typedef unsigned int u32;
typedef __attribute__((ext_vector_type(8))) short short8;
typedef __attribute__((ext_vector_type(4))) float f32x4;

#define AS1 __attribute__((address_space(1)))
#define AS3 __attribute__((address_space(3)))

__device__ __forceinline__ void gll16(const void* g, void* l) {
  __builtin_amdgcn_global_load_lds((AS1 const void*)g, (AS3 void*)l, 16, 0, 0);
}

__device__ __forceinline__ u16 f2bf(float f) {
  u32 u = __float_as_uint(f);
  u32 r = (u + 0x7fffu + ((u >> 16) & 1u)) >> 16;
  return (u16)r;
}

// ---------- convert x fp32 -> bf16 ----------
__global__ void cvt_x(const float* __restrict__ x, u16* __restrict__ xb) {
  int i = blockIdx.x * blockDim.x + threadIdx.x;
  const int total = T_ * D_ / 8;
  for (; i < total; i += gridDim.x * blockDim.x) {
    float4 v0 = ((const float4*)x)[2*i];
    float4 v1 = ((const float4*)x)[2*i+1];
    uint4 o;
    o.x = (u32)f2bf(v0.x) | ((u32)f2bf(v0.y) << 16);
    o.y = (u32)f2bf(v0.z) | ((u32)f2bf(v0.w) << 16);
    o.z = (u32)f2bf(v1.x) | ((u32)f2bf(v1.y) << 16);
    o.w = (u32)f2bf(v1.z) | ((u32)f2bf(v1.w) << 16);
    ((uint4*)xb)[i] = o;
  }
}

// ---------- convert + transpose W1[e][d][f] -> w1t[e][f][d] bf16 ----------
__global__ void cvt_w1(const float* __restrict__ W1, u16* __restrict__ w1t) {
  __shared__ float tile[64][65];
  int e = blockIdx.z;
  int d0 = blockIdx.y * 64, f0 = blockIdx.x * 64;
  int tid = threadIdx.x;
  int r = tid >> 2, cs = (tid & 3) * 16;
  const float* src = W1 + ((size_t)e * D_ + d0) * F_ + f0;
  #pragma unroll
  for (int j = 0; j < 4; ++j) {
    float4 v = *(const float4*)&src[(size_t)r * F_ + cs + j*4];
    tile[r][cs + j*4 + 0] = v.x;
    tile[r][cs + j*4 + 1] = v.y;
    tile[r][cs + j*4 + 2] = v.z;
    tile[r][cs + j*4 + 3] = v.w;
  }
  __syncthreads();
  u32 vals[8];
  #pragma unroll
  for (int j = 0; j < 8; ++j) {
    u32 lo = f2bf(tile[cs + 2*j][r]);
    u32 hi = f2bf(tile[cs + 2*j + 1][r]);
    vals[j] = lo | (hi << 16);
  }
  uint4 A = {vals[0], vals[1], vals[2], vals[3]};
  uint4 Bv = {vals[4], vals[5], vals[6], vals[7]};
  uint4* dst = (uint4*)(w1t + ((size_t)e * F_ + f0 + r) * D_ + d0 + cs);
  dst[0] = A;
  dst[1] = Bv;
}

// ---------- router: fp32 logits, top-2, softmax -> dense gates [T][E] ----------
__global__ void router(const float* __restrict__ x, const float* __restrict__ Wg,
                       const float* __restrict__ bg, float* __restrict__ gdense) {
  int wave = (blockIdx.x * blockDim.x + threadIdx.x) >> 6;
  int lane = threadIdx.x & 63;
  if (wave >= T_) return;
  const float* xr = x + (size_t)wave * D_;
  float acc[8] = {0,0,0,0,0,0,0,0};
  for (int i = 0; i < D_/64; ++i) {
    int d = i*64 + lane;
    float xv = xr[d];
    const float4* wr = (const float4*)(Wg + (size_t)d * E_);
    float4 wa = wr[0], wb2 = wr[1];
    acc[0] += xv * wa.x;  acc[1] += xv * wa.y;
    acc[2] += xv * wa.z;  acc[3] += xv * wa.w;
    acc[4] += xv * wb2.x; acc[5] += xv * wb2.y;
    acc[6] += xv * wb2.z; acc[7] += xv * wb2.w;
  }
  #pragma unroll
  for (int e = 0; e < 8; ++e) {
    #pragma unroll
    for (int s = 32; s > 0; s >>= 1) acc[e] += __shfl_xor(acc[e], s);
  }
  if (lane == 0) {
    float v[8];
    #pragma unroll
    for (int e = 0; e < 8; ++e) v[e] = acc[e] + bg[e];
    int i1 = -1, i2 = -1;
    float b1v = -1e30f, b2v = -1e30f;
    #pragma unroll
    for (int e = 0; e < 8; ++e) {
      float vv = v[e];
      if (vv > b1v) { b2v = b1v; i2 = i1; b1v = vv; i1 = e; }
      else if (vv > b2v) { b2v = vv; i2 = e; }
    }
    float e2 = __expf(b2v - b1v);
    float inv = 1.f / (1.f + e2);
    float* gr = gdense + (size_t)wave * E_;
    #pragma unroll
    for (int e = 0; e < 8; ++e) gr[e] = 0.f;
    gr[i1] = inv;
    gr[i2] = e2 * inv;
  }
}

// ---------- compaction: per (b,e) ordered token list, padded to 128 ----------
__global__ void compact(const float* __restrict__ gdense, int* __restrict__ lists,
                        float* __restrict__ glist, int* __restrict__ cntp,
                        float* __restrict__ G) {
  int be = blockIdx.x;
  int b = be >> 3, e = be & 7;
  __shared__ int warp_off[4];
  __shared__ float wsum[4];
  int tid = threadIdx.x;
  int lane = tid & 63, w = tid >> 6;
  int base = 0;
  float gsum = 0.f;
  for (int c = 0; c < N_; c += 256) {
    int t = b * N_ + c + tid;
    float g = gdense[(size_t)t * E_ + e];
    gsum += g;
    bool sel = g > 0.f;
    unsigned long long m = __ballot(sel);
    int my = __popcll(m & ((1ull << lane) - 1ull));
    int wcnt = __popcll(m);
    if (lane == 0) warp_off[w] = wcnt;
    __syncthreads();
    int off = 0;
    for (int i = 0; i < w; ++i) off += warp_off[i];
    int tot = warp_off[0] + warp_off[1] + warp_off[2] + warp_off[3];
    if (sel) {
      int pos = base + off + my;
      lists[be * N_ + pos] = t;
      glist[be * N_ + pos] = g;
    }
    base += tot;
    __syncthreads();
  }
  int padded = (base + 127) & ~127;
  for (int p = base + tid; p < padded; p += 256) {
    lists[be * N_ + p] = b * N_;
    glist[be * N_ + p] = 0.f;
  }
  if (tid == 0) cntp[be] = padded;
  #pragma unroll
  for (int s = 32; s > 0; s >>= 1) gsum += __shfl_xor(gsum, s);
  if (lane == 0) wsum[w] = gsum;
  __syncthreads();
  if (tid == 0) G[be] = wsum[0] + wsum[1] + wsum[2] + wsum[3];
}

// ---------- out init with bias-2 term: out[b][h] = sum_e G[b,e]*b2[e][h] ----------
__global__ void init_out(const float* __restrict__ G, const float* __restrict__ b2,
                         float* __restrict__ out) {
  int i = blockIdx.x * 256 + threadIdx.x;
  int b = i >> 10, h = i & 1023;
  float acc = 0.f;
  #pragma unroll
  for (int e = 0; e < 8; ++e) acc += G[b * E_ + e] * b2[e * H_ + h];
  out[i] = acc;
}

// ---------- GEMM1: s[be][f] += sum_rows gate * relu(Xsel @ W1[e] + b1[e]) ----------
// m97-style 128x128 tile, BK=32, 4 waves, mfma_f32_16x16x32_bf16, global_load_lds w16.
__launch_bounds__(256)
__global__ void gemm1(const u16* __restrict__ xb, const u16* __restrict__ w1t,
                      const float* __restrict__ b1, const int* __restrict__ lists,
                      const float* __restrict__ glist, const int* __restrict__ cntp,
                      float* __restrict__ sbuf) {
  int bid = blockIdx.x;
  int be = bid >> 9;
  int rem = bid & 511;
  int ft = rem >> 4;
  int chunk = rem & 15;
  int cnt = cntp[be];
  if (chunk * 128 >= cnt) return;
  int e = be & 7;
  int mbase = chunk * 128;
  int fbase = ft * 128;

  __shared__ u16 sA[2][4096];
  __shared__ u16 sB[2][4096];
  __shared__ float sGate[128];

  int tid = threadIdx.x;
  int lane = tid & 63;
  int w = tid >> 6;
  int wm = w >> 1, wn = w & 1;

  int row = tid & 127;
  int t = lists[be * N_ + mbase + row];
  if (tid < 128) sGate[tid] = glist[be * N_ + mbase + tid];

  const u16* aSrc = xb + (size_t)t * D_ + ((tid >> 7) * 8);
  const u16* bSrc = w1t + ((size_t)(e * F_ + fbase + row)) * D_ + ((tid >> 7) * 8);
  int wb = w << 9;  // wave-uniform LDS base (elements) per 4KB half

  f32x4 acc[4][4];
  #pragma unroll
  for (int i = 0; i < 4; ++i)
    #pragma unroll
    for (int j = 0; j < 4; ++j) acc[i][j] = (f32x4){0.f, 0.f, 0.f, 0.f};

  // prologue: stage k-tile 0 into buf 0
  gll16(aSrc + 0,  &sA[0][wb]);
  gll16(aSrc + 16, &sA[0][2048 + wb]);
  gll16(bSrc + 0,  &sB[0][wb]);
  gll16(bSrc + 16, &sB[0][2048 + wb]);

  const int nk = D_ / 32;
  int kg = (lane >> 4) * 128;   // k-group block in short8 units
  int fr = lane & 15;

  for (int kk = 0; kk < nk; ++kk) {
    int buf = kk & 1;
    __syncthreads();   // drains vmcnt -> tile kk ready; all reads of other buf done
    if (kk + 1 < nk) {
      int k0 = (kk + 1) * 32;
      int nb = buf ^ 1;
      gll16(aSrc + k0,      &sA[nb][wb]);
      gll16(aSrc + k0 + 16, &sA[nb][2048 + wb]);
      gll16(bSrc + k0,      &sB[nb][wb]);
      gll16(bSrc + k0 + 16, &sB[nb][2048 + wb]);
    }
    const short8* Ab = (const short8*)&sA[buf][0];
    const short8* Bb = (const short8*)&sB[buf][0];
    short8 a[4], bfr[4];
    #pragma unroll
    for (int mi = 0; mi < 4; ++mi) a[mi] = Ab[kg + wm * 64 + mi * 16 + fr];
    #pragma unroll
    for (int ni = 0; ni < 4; ++ni) bfr[ni] = Bb[kg + wn * 64 + ni * 16 + fr];
    #pragma unroll
    for (int mi = 0; mi < 4; ++mi)
      #pragma unroll
      for (int ni = 0; ni < 4; ++ni)
        acc[mi][ni] = __builtin_amdgcn_mfma_f32_16x16x32_bf16(a[mi], bfr[ni], acc[mi][ni], 0, 0, 0);
  }

  // epilogue: h = relu(acc + b1) * gate; column-sum over rows; atomicAdd into s
  float b1f[4];
  #pragma unroll
  for (int ni = 0; ni < 4; ++ni)
    b1f[ni] = b1[e * F_ + fbase + wn * 64 + ni * 16 + fr];
  int rg = (lane >> 4) * 4;
  #pragma unroll
  for (int ni = 0; ni < 4; ++ni) {
    float csum = 0.f;
    #pragma unroll
    for (int mi = 0; mi < 4; ++mi) {
      int rb = wm * 64 + mi * 16 + rg;
      #pragma unroll
      for (int r = 0; r < 4; ++r) {
        float v = acc[mi][ni][r] + b1f[ni];
        v = fmaxf(v, 0.f);
        csum += v * sGate[rb + r];
      }
    }
    csum += __shfl_xor(csum, 16);
    csum += __shfl_xor(csum, 32);
    if (lane < 16)
      atomicAdd(&sbuf[be * F_ + fbase + wn * 64 + ni * 16 + lane], csum);
  }
}

// ---------- GEMM2: out[b][h] += sum_f s[b,e,f] * W2[e][f][h] (memory-bound) ----------
__global__ void gemm2(const float* __restrict__ sbuf, const float* __restrict__ W2,
                      float* __restrict__ out) {
  int fc = blockIdx.x;   // 16 chunks of 256 f
  int ht = blockIdx.y;   // 4 tiles of 256 h
  int e  = blockIdx.z;   // 8 experts
  __shared__ float sS[8][256];
  int tid = threadIdx.x;
  #pragma unroll
  for (int b = 0; b < 8; ++b)
    sS[b][tid] = sbuf[((size_t)(b * E_ + e)) * F_ + fc * 256 + tid];
  __syncthreads();
  int h = ht * 256 + tid;
  float acc[8] = {0,0,0,0,0,0,0,0};
  const float* w2p = W2 + (size_t)e * F_ * H_ + (size_t)(fc * 256) * H_ + h;
  for (int f = 0; f < 256; ++f) {
    float wv = w2p[(size_t)f * H_];
    #pragma unroll
    for (int b = 0; b < 8; ++b) acc[b] += sS[b][f] * wv;
  }
  #pragma unroll
  for (int b = 0; b < 8; ++b) atomicAdd(&out[b * H_ + h], acc[b]);
}

extern "C" void kernel_launch(void* const* d_in, const int* in_sizes, int n_in,
                              void* d_out, int out_size, void* d_ws, size_t ws_size,
                              hipStream_t stream) {
  const float* x  = (const float*)d_in[0];
  const float* Wg = (const float*)d_in[1];
  const float* bg = (const float*)d_in[2];
  const float* W1 = (const float*)d_in[3];
  const float* b1 = (const float*)d_in[4];
  const float* W2 = (const float*)d_in[5];
  const float* b2 = (const float*)d_in[6];
  // d_in[7] = top_k (assumed 2, per problem spec)
  float* out = (float*)d_out;

  char* ws = (char*)d_ws;
  u16*   xb     = (u16*)(ws);
  u16*   w1t    = (u16*)(ws + 33554432);
  float* gdense = (float*)(ws + 100663296);
  int*   lists  = (int*)(ws + 101187584);
  float* glist  = (float*)(ws + 101711872);
  int*   cntp   = (int*)(ws + 102236160);
  float* G      = (float*)(ws + 102236416);
  float* sbuf   = (float*)(ws + 102236672);

  hipMemsetAsync(sbuf, 0, (size_t)64 * F_ * sizeof(float), stream);
  cvt_x<<<8192, 256, 0, stream>>>(x, xb);
  cvt_w1<<<dim3(F_/64, D_/64, E_), 256, 0, stream>>>(W1, w1t);
  router<<<T_/4, 256, 0, stream>>>(x, Wg, bg, gdense);
  compact<<<64, 256, 0, stream>>>(gdense, lists, glist, cntp, G);
  init_out<<<(B_*H_)/256, 256, 0, stream>>>(G, b2, out);
  gemm1<<<64*16*32, 256, 0, stream>>>(xb, w1t, b1, lists, glist, cntp, sbuf);
  gemm2<<<dim3(16, 4, 8), 256, 0, stream>>>(sbuf, W2, out);
}

// Round 2
// 797.243 us; speedup vs baseline: 2.9126x; 2.9126x over previous
//
#include <hip/hip_runtime.h>
#include <stdint.h>

#define B_ 8
#define N_ 2048
#define D_ 1024
#define E_ 8
#define F_ 4096
#define H_ 1024
#define T_ (B_*N_)

typedef unsigned short u16;
typedef unsigned int u32;
typedef __attribute__((ext_vector_type(8))) short short8;
typedef __attribute__((ext_vector_type(4))) float f32x4;

#define AS1 __attribute__((address_space(1)))
#define AS3 __attribute__((address_space(3)))

__device__ __forceinline__ void gll16(const void* g, void* l) {
  __builtin_amdgcn_global_load_lds((AS1 const void*)g, (AS3 void*)l, 16, 0, 0);
}

__device__ __forceinline__ u16 f2bf(float f) {
  u32 u = __float_as_uint(f);
  u32 r = (u + 0x7fffu + ((u >> 16) & 1u)) >> 16;
  return (u16)r;
}

// ---------- convert x fp32 -> bf16 ----------
__global__ void cvt_x(const float* __restrict__ x, u16* __restrict__ xb) {
  int i = blockIdx.x * blockDim.x + threadIdx.x;
  const int total = T_ * D_ / 8;
  for (; i < total; i += gridDim.x * blockDim.x) {
    float4 v0 = ((const float4*)x)[2*i];
    float4 v1 = ((const float4*)x)[2*i+1];
    uint4 o;
    o.x = (u32)f2bf(v0.x) | ((u32)f2bf(v0.y) << 16);
    o.y = (u32)f2bf(v0.z) | ((u32)f2bf(v0.w) << 16);
    o.z = (u32)f2bf(v1.x) | ((u32)f2bf(v1.y) << 16);
    o.w = (u32)f2bf(v1.z) | ((u32)f2bf(v1.w) << 16);
    ((uint4*)xb)[i] = o;
  }
}

// ---------- convert + transpose W1[e][d][f] -> w1t[e][f][d] bf16 ----------
__global__ void cvt_w1(const float* __restrict__ W1, u16* __restrict__ w1t) {
  __shared__ float tile[64][65];
  int e = blockIdx.z;
  int d0 = blockIdx.y * 64, f0 = blockIdx.x * 64;
  int tid = threadIdx.x;
  int r = tid >> 2, cs = (tid & 3) * 16;
  const float* src = W1 + ((size_t)e * D_ + d0) * F_ + f0;
  #pragma unroll
  for (int j = 0; j < 4; ++j) {
    float4 v = *(const float4*)&src[(size_t)r * F_ + cs + j*4];
    tile[r][cs + j*4 + 0] = v.x;
    tile[r][cs + j*4 + 1] = v.y;
    tile[r][cs + j*4 + 2] = v.z;
    tile[r][cs + j*4 + 3] = v.w;
  }
  __syncthreads();
  u32 vals[8];
  #pragma unroll
  for (int j = 0; j < 8; ++j) {
    u32 lo = f2bf(tile[cs + 2*j][r]);
    u32 hi = f2bf(tile[cs + 2*j + 1][r]);
    vals[j] = lo | (hi << 16);
  }
  uint4 A = {vals[0], vals[1], vals[2], vals[3]};
  uint4 Bv = {vals[4], vals[5], vals[6], vals[7]};
  uint4* dst = (uint4*)(w1t + ((size_t)e * F_ + f0 + r) * D_ + d0 + cs);
  dst[0] = A;
  dst[1] = Bv;
}

// ---------- router: fp32 logits, top-2, softmax -> dense gates [T][E] ----------
__global__ void router(const float* __restrict__ x, const float* __restrict__ Wg,
                       const float* __restrict__ bg, float* __restrict__ gdense) {
  int wave = (blockIdx.x * blockDim.x + threadIdx.x) >> 6;
  int lane = threadIdx.x & 63;
  if (wave >= T_) return;
  const float* xr = x + (size_t)wave * D_;
  float acc[8] = {0,0,0,0,0,0,0,0};
  for (int i = 0; i < D_/64; ++i) {
    int d = i*64 + lane;
    float xv = xr[d];
    const float4* wr = (const float4*)(Wg + (size_t)d * E_);
    float4 wa = wr[0], wb2 = wr[1];
    acc[0] += xv * wa.x;  acc[1] += xv * wa.y;
    acc[2] += xv * wa.z;  acc[3] += xv * wa.w;
    acc[4] += xv * wb2.x; acc[5] += xv * wb2.y;
    acc[6] += xv * wb2.z; acc[7] += xv * wb2.w;
  }
  #pragma unroll
  for (int e = 0; e < 8; ++e) {
    #pragma unroll
    for (int s = 32; s > 0; s >>= 1) acc[e] += __shfl_xor(acc[e], s);
  }
  if (lane == 0) {
    float v[8];
    #pragma unroll
    for (int e = 0; e < 8; ++e) v[e] = acc[e] + bg[e];
    int i1 = -1, i2 = -1;
    float b1v = -1e30f, b2v = -1e30f;
    #pragma unroll
    for (int e = 0; e < 8; ++e) {
      float vv = v[e];
      if (vv > b1v) { b2v = b1v; i2 = i1; b1v = vv; i1 = e; }
      else if (vv > b2v) { b2v = vv; i2 = e; }
    }
    float e2 = __expf(b2v - b1v);
    float inv = 1.f / (1.f + e2);
    float* gr = gdense + (size_t)wave * E_;
    #pragma unroll
    for (int e = 0; e < 8; ++e) gr[e] = 0.f;
    gr[i1] = inv;
    gr[i2] = e2 * inv;
  }
}

// ---------- compaction: per (b,e) ordered token list, padded to 128 ----------
__global__ void compact(const float* __restrict__ gdense, int* __restrict__ lists,
                        float* __restrict__ glist, int* __restrict__ cntp,
                        float* __restrict__ G) {
  int be = blockIdx.x;
  int b = be >> 3, e = be & 7;
  __shared__ int warp_off[4];
  __shared__ float wsum[4];
  int tid = threadIdx.x;
  int lane = tid & 63, w = tid >> 6;
  int base = 0;
  float gsum = 0.f;
  for (int c = 0; c < N_; c += 256) {
    int t = b * N_ + c + tid;
    float g = gdense[(size_t)t * E_ + e];
    gsum += g;
    bool sel = g > 0.f;
    unsigned long long m = __ballot(sel);
    int my = __popcll(m & ((1ull << lane) - 1ull));
    int wcnt = __popcll(m);
    if (lane == 0) warp_off[w] = wcnt;
    __syncthreads();
    int off = 0;
    for (int i = 0; i < w; ++i) off += warp_off[i];
    int tot = warp_off[0] + warp_off[1] + warp_off[2] + warp_off[3];
    if (sel) {
      int pos = base + off + my;
      lists[be * N_ + pos] = t;
      glist[be * N_ + pos] = g;
    }
    base += tot;
    __syncthreads();
  }
  int padded = (base + 127) & ~127;
  for (int p = base + tid; p < padded; p += 256) {
    lists[be * N_ + p] = b * N_;
    glist[be * N_ + p] = 0.f;
  }
  if (tid == 0) cntp[be] = padded;
  #pragma unroll
  for (int s = 32; s > 0; s >>= 1) gsum += __shfl_xor(gsum, s);
  if (lane == 0) wsum[w] = gsum;
  __syncthreads();
  if (tid == 0) G[be] = wsum[0] + wsum[1] + wsum[2] + wsum[3];
}

// ---------- out init with bias-2 term: out[b][h] = sum_e G[b,e]*b2[e][h] ----------
__global__ void init_out(const float* __restrict__ G, const float* __restrict__ b2,
                         float* __restrict__ out) {
  int i = blockIdx.x * 256 + threadIdx.x;
  int b = i >> 10, h = i & 1023;
  float acc = 0.f;
  #pragma unroll
  for (int e = 0; e < 8; ++e) acc += G[b * E_ + e] * b2[e * H_ + h];
  out[i] = acc;
}

// stage one 128x32 bf16 k-tile pair (A and B) into LDS slot
__device__ __forceinline__ void stage4(const u16* aSrc, const u16* bSrc, int k0,
                                       u16* sa, u16* sb, int wb) {
  gll16(aSrc + k0,      sa + wb);
  gll16(aSrc + k0 + 16, sa + 2048 + wb);
  gll16(bSrc + k0,      sb + wb);
  gll16(bSrc + k0 + 16, sb + 2048 + wb);
}

// ---------- GEMM1: s[be][f] = sum_rows gate * relu(Xsel @ W1[e] + b1[e]) ----------
// One block per (be, ftile). Chunk loop inside. Depth-2 counted-vmcnt pipeline,
// 3 LDS buffers, raw s_barrier (loads stay in flight across barriers).
__launch_bounds__(256, 3)
__global__ void gemm1(const u16* __restrict__ xb, const u16* __restrict__ w1t,
                      const float* __restrict__ b1, const int* __restrict__ lists,
                      const float* __restrict__ glist, const int* __restrict__ cntp,
                      float* __restrict__ sbuf) {
  int bid = blockIdx.x;
  // XCD-bijective swizzle: 2048 % 8 == 0; each XCD gets 8 contiguous be's
  int orig = (bid & 7) * 256 + (bid >> 3);
  int be = orig >> 5;
  int ft = orig & 31;
  int e = be & 7;
  int fbase = ft * 128;
  int nchunks = cntp[be] >> 7;

  __shared__ u16 sA[3][4096];
  __shared__ u16 sB[3][4096];
  __shared__ float sGate[128];
  __shared__ float sOut[128];

  int tid = threadIdx.x;
  int lane = tid & 63;
  int w = tid >> 6;
  int wm = w >> 1, wn = w & 1;
  int row = tid & 127;
  int koff = (tid >> 7) * 8;
  int wb = w << 9;  // wave-uniform LDS element base

  const u16* bSrc = w1t + ((size_t)(e * F_ + fbase + row)) * D_ + koff;

  int fr = lane & 15;
  int kg = (lane >> 4) * 128;
  int rg = (lane >> 4) * 4;

  float b1f[4];
  #pragma unroll
  for (int ni = 0; ni < 4; ++ni)
    b1f[ni] = b1[e * F_ + fbase + wn * 64 + ni * 16 + fr];

  float osum[4] = {0.f, 0.f, 0.f, 0.f};

  for (int chunk = 0; chunk < nchunks; ++chunk) {
    __syncthreads();  // prev epilogue done with sGate; vmcnt==0 here
    int t = lists[be * N_ + chunk * 128 + row];
    if (tid < 128) sGate[tid] = glist[be * N_ + chunk * 128 + tid];
    const u16* aSrc = xb + (size_t)t * D_ + koff;
    __syncthreads();  // sGate visible to all waves

    f32x4 acc[4][4];
    #pragma unroll
    for (int i = 0; i < 4; ++i)
      #pragma unroll
      for (int j = 0; j < 4; ++j) acc[i][j] = (f32x4){0.f, 0.f, 0.f, 0.f};

    // prologue: tiles 0 and 1 in flight (8 vmem insts/wave)
    stage4(aSrc, bSrc, 0,  sA[0], sB[0], wb);
    stage4(aSrc, bSrc, 32, sA[1], sB[1], wb);

    const int nk = D_ / 32;  // 32
    for (int kk = 0; kk < nk; ++kk) {
      int slot = kk % 3;
      if (kk + 2 < nk)
        stage4(aSrc, bSrc, (kk + 2) * 32, sA[(kk + 2) % 3], sB[(kk + 2) % 3], wb);
      // counted wait: tile kk complete (its 4 insts are the oldest in flight)
      if (kk + 2 < nk)      asm volatile("s_waitcnt vmcnt(8)" ::: "memory");
      else if (kk + 1 < nk) asm volatile("s_waitcnt vmcnt(4)" ::: "memory");
      else                  asm volatile("s_waitcnt vmcnt(0)" ::: "memory");
      __builtin_amdgcn_s_barrier();        // all waves' tile-kk stores visible
      __builtin_amdgcn_sched_barrier(0);   // no ds_read hoisting above barrier
      const short8* Ab = (const short8*)&sA[slot][0];
      const short8* Bb = (const short8*)&sB[slot][0];
      short8 a[4], bfr[4];
      #pragma unroll
      for (int mi = 0; mi < 4; ++mi) a[mi] = Ab[kg + wm * 64 + mi * 16 + fr];
      #pragma unroll
      for (int ni = 0; ni < 4; ++ni) bfr[ni] = Bb[kg + wn * 64 + ni * 16 + fr];
      #pragma unroll
      for (int mi = 0; mi < 4; ++mi)
        #pragma unroll
        for (int ni = 0; ni < 4; ++ni)
          acc[mi][ni] = __builtin_amdgcn_mfma_f32_16x16x32_bf16(a[mi], bfr[ni], acc[mi][ni], 0, 0, 0);
      __builtin_amdgcn_sched_barrier(0);   // keep reads before this fence
      __builtin_amdgcn_s_barrier();        // reads done -> oldest slot reusable
    }

    // per-chunk epilogue: relu(acc + b1) * gate, accumulate column partials
    #pragma unroll
    for (int ni = 0; ni < 4; ++ni) {
      float partial = 0.f;
      #pragma unroll
      for (int mi = 0; mi < 4; ++mi) {
        int rb = wm * 64 + mi * 16 + rg;
        #pragma unroll
        for (int r = 0; r < 4; ++r) {
          float v = acc[mi][ni][r] + b1f[ni];
          v = fmaxf(v, 0.f);
          partial += v * sGate[rb + r];
        }
      }
      osum[ni] += partial;
    }
  }

  // final reduce: across k-groups (lanes), then across wm waves via LDS
  #pragma unroll
  for (int ni = 0; ni < 4; ++ni) {
    osum[ni] += __shfl_xor(osum[ni], 16);
    osum[ni] += __shfl_xor(osum[ni], 32);
  }
  __syncthreads();
  if (wm == 0 && lane < 16) {
    #pragma unroll
    for (int ni = 0; ni < 4; ++ni)
      sOut[wn * 64 + ni * 16 + lane] = osum[ni];
  }
  __syncthreads();
  if (wm == 1 && lane < 16) {
    #pragma unroll
    for (int ni = 0; ni < 4; ++ni) {
      int fc = wn * 64 + ni * 16 + lane;
      sbuf[(size_t)be * F_ + fbase + fc] = sOut[fc] + osum[ni];
    }
  }
}

// ---------- GEMM2: out[b][h] += sum_f s[b,e,f] * W2[e][f][h] (memory-bound) ----------
__global__ void gemm2(const float* __restrict__ sbuf, const float* __restrict__ W2,
                      float* __restrict__ out) {
  int fc = blockIdx.x;   // 16 chunks of 256 f
  int ht = blockIdx.y;   // 4 tiles of 256 h
  int e  = blockIdx.z;   // 8 experts
  __shared__ float sS[8][256];
  int tid = threadIdx.x;
  #pragma unroll
  for (int b = 0; b < 8; ++b)
    sS[b][tid] = sbuf[((size_t)(b * E_ + e)) * F_ + fc * 256 + tid];
  __syncthreads();
  int h = ht * 256 + tid;
  float acc[8] = {0,0,0,0,0,0,0,0};
  const float* w2p = W2 + (size_t)e * F_ * H_ + (size_t)(fc * 256) * H_ + h;
  for (int f = 0; f < 256; ++f) {
    float wv = w2p[(size_t)f * H_];
    #pragma unroll
    for (int b = 0; b < 8; ++b) acc[b] += sS[b][f] * wv;
  }
  #pragma unroll
  for (int b = 0; b < 8; ++b) atomicAdd(&out[b * H_ + h], acc[b]);
}

extern "C" void kernel_launch(void* const* d_in, const int* in_sizes, int n_in,
                              void* d_out, int out_size, void* d_ws, size_t ws_size,
                              hipStream_t stream) {
  const float* x  = (const float*)d_in[0];
  const float* Wg = (const float*)d_in[1];
  const float* bg = (const float*)d_in[2];
  const float* W1 = (const float*)d_in[3];
  const float* b1 = (const float*)d_in[4];
  const float* W2 = (const float*)d_in[5];
  const float* b2 = (const float*)d_in[6];
  float* out = (float*)d_out;

  char* ws = (char*)d_ws;
  u16*   xb     = (u16*)(ws);
  u16*   w1t    = (u16*)(ws + 33554432);
  float* gdense = (float*)(ws + 100663296);
  int*   lists  = (int*)(ws + 101187584);
  float* glist  = (float*)(ws + 101711872);
  int*   cntp   = (int*)(ws + 102236160);
  float* G      = (float*)(ws + 102236416);
  float* sbuf   = (float*)(ws + 102236672);

  cvt_x<<<8192, 256, 0, stream>>>(x, xb);
  cvt_w1<<<dim3(F_/64, D_/64, E_), 256, 0, stream>>>(W1, w1t);
  router<<<T_/4, 256, 0, stream>>>(x, Wg, bg, gdense);
  compact<<<64, 256, 0, stream>>>(gdense, lists, glist, cntp, G);
  init_out<<<(B_*H_)/256, 256, 0, stream>>>(G, b2, out);
  gemm1<<<2048, 256, 0, stream>>>(xb, w1t, b1, lists, glist, cntp, sbuf);
  gemm2<<<dim3(16, 4, 8), 256, 0, stream>>>(sbuf, W2, out);
}